// Round 18
// baseline (741.592 us; speedup 1.0000x reference)
//
#include <hip/hip_runtime.h>
#include <hip/hip_bf16.h>

#define NN 50000
#define NE 800000
#define EPSV 1e-5f
#define NB 49   // scan blocks: ceil(NN/1024)

typedef _Float16 h8 __attribute__((ext_vector_type(8)));
typedef float    f4 __attribute__((ext_vector_type(4)));

// ---------------- graph preprocessing ----------------

__global__ void k_deg(const int* __restrict__ dst, int* __restrict__ deg){
  int e = blockIdx.x*blockDim.x + threadIdx.x;
  if(e < NE) atomicAdd(&deg[dst[e]], 1);
}

__global__ void k_logdeg(const int* __restrict__ deg, float* __restrict__ logdeg,
                         float* __restrict__ dsum){
  int i = blockIdx.x*blockDim.x + threadIdx.x;
  float v = 0.f;
  if(i < NN){ v = log1pf((float)deg[i]); logdeg[i] = v; }
  __shared__ float sh[256];
  sh[threadIdx.x] = v; __syncthreads();
  for(int off=128; off>0; off>>=1){
    if(threadIdx.x < off) sh[threadIdx.x] += sh[threadIdx.x+off];
    __syncthreads();
  }
  if(threadIdx.x == 0) atomicAdd(dsum, sh[0]);
}

__global__ void k_scalers(const float* __restrict__ logdeg, const float* __restrict__ dsum,
                          float* __restrict__ amp, float* __restrict__ att){
  int i = blockIdx.x*blockDim.x + threadIdx.x;
  if(i >= NN) return;
  float delta = dsum[0] / (float)NN;
  float ld = logdeg[i];
  amp[i] = ld / delta;
  att[i] = (ld > 0.f) ? (delta / fmaxf(ld, 1e-6f)) : 1.f;
}

// 3-phase parallel exclusive scan of deg -> rowptr (+cursor copy)
__global__ void k_scan1(const int* __restrict__ deg, int* __restrict__ rowptr,
                        int* __restrict__ bsum){
  __shared__ int buf[1024];
  int tid = threadIdx.x;
  int i = blockIdx.x*1024 + tid;
  int v = (i < NN) ? deg[i] : 0;
  buf[tid] = v; __syncthreads();
  for(int off=1; off<1024; off<<=1){
    int t = (tid >= off) ? buf[tid-off] : 0;
    __syncthreads();
    buf[tid] += t;
    __syncthreads();
  }
  if(i < NN) rowptr[i] = buf[tid] - v;
  if(tid == 1023) bsum[blockIdx.x] = buf[1023];
}

__global__ void k_scan2(int* __restrict__ bsum){
  if(threadIdx.x == 0){
    int s = 0;
    for(int b = 0; b < NB; b++){ int t = bsum[b]; bsum[b] = s; s += t; }
    bsum[NB] = s;
  }
}

__global__ void k_scan3(int* __restrict__ rowptr, int* __restrict__ cursor,
                        const int* __restrict__ bsum){
  int i = blockIdx.x*256 + threadIdx.x;
  if(i < NN){
    int v = rowptr[i] + bsum[i >> 10];
    rowptr[i] = v; cursor[i] = v;
  }
  if(i == NN) rowptr[NN] = bsum[NB];
}

__global__ void k_fill(const int* __restrict__ src, const int* __restrict__ dst,
                       int* __restrict__ cursor, int* __restrict__ colidx){
  int e = blockIdx.x*blockDim.x + threadIdx.x;
  if(e < NE){
    int pos = atomicAdd(&cursor[dst[e]], 1);
    colidx[pos] = src[e];
  }
}

__global__ void k_cvtx(const float* __restrict__ x, _Float16* __restrict__ act){
  int i = blockIdx.x*256 + threadIdx.x;
  if(i < NN*64) act[i] = (_Float16)x[i];
}

// identity BN coefficients for layer 1
__global__ void k_coef_id(float* __restrict__ cs, float* __restrict__ csh,
                          _Float16* __restrict__ cs16, _Float16* __restrict__ csh16){
  int c = threadIdx.x;
  cs[c] = 1.f; csh[c] = 0.f;
  cs16[c] = (_Float16)1.f; csh16[c] = (_Float16)0.f;
}

// BN coefficients from stats: v' = a*v + b with a=inv*gamma, b=beta-mean*a
__global__ void k_bn_coef(const float* __restrict__ colsum, const float* __restrict__ colss,
                          const float* __restrict__ gamma, const float* __restrict__ beta,
                          int dout, float* __restrict__ cs, float* __restrict__ csh,
                          _Float16* __restrict__ cs16, _Float16* __restrict__ csh16){
  int c = threadIdx.x;
  if(c >= dout) return;
  float mean = colsum[c] / (float)NN;
  float var  = colss[c] / (float)NN - mean*mean;
  float inv  = rsqrtf(fmaxf(var, 0.f) + EPSV);
  float a = inv * gamma[c];
  float b = beta[c] - mean * a;
  cs[c] = a; csh[c] = b;
  cs16[c] = (_Float16)a; csh16[c] = (_Float16)b;
}

// ---------------- aggregation (templated on D): 8 cols/lane, 16 B loads ----------------
// Reads RAW act; applies per-column affine (a,b) in the epilogue:
// mean'=a*mean+b ; min/max swap on a<0 ; std'=sqrt(a^2*var+eps).
// aggs[chunk][n*256 + {0,64,128,192} + cl] = mean|min|max|std

template<int D>
__global__ __launch_bounds__(256) void k_agg8(
    const _Float16* __restrict__ act,
    const int* __restrict__ rowptr, const int* __restrict__ colidx,
    const float* __restrict__ cs, const float* __restrict__ csh,
    _Float16* __restrict__ aggs, size_t aggN)
{
  constexpr int LPN = D >> 3;       // lanes per node: 8/16/32
  constexpr int NPW = 64 / LPN;     // nodes per wave: 8/4/2
  int wv = threadIdx.x >> 6, lane = threadIdx.x & 63;
  int n = blockIdx.x*(NPW*4) + wv*NPW + (lane / LPN);
  int c = (lane % LPN) * 8;         // 8 adjacent feature cols
  if(n >= NN) return;
  int beg = rowptr[n], end = rowptr[n+1];
  const _Float16* hp = act + c;

  float s[8], q[8], mn[8], mx[8];
  #pragma unroll
  for(int j = 0; j < 8; j++){ s[j]=0.f; q[j]=0.f; mn[j]=INFINITY; mx[j]=-INFINITY; }

#define ACC8(v) { _Pragma("unroll") for(int j=0;j<8;j++){ float a=(float)(v)[j]; \
    s[j]+=a; q[j]+=a*a; mn[j]=fminf(mn[j],a); mx[j]=fmaxf(mx[j],a); } }

  int e = beg;
  for(; e+8 <= end; e+=8){
    int i0=colidx[e],   i1=colidx[e+1], i2=colidx[e+2], i3=colidx[e+3];
    int i4=colidx[e+4], i5=colidx[e+5], i6=colidx[e+6], i7=colidx[e+7];
    h8 v0 = *(const h8*)(hp + (size_t)i0*D);
    h8 v1 = *(const h8*)(hp + (size_t)i1*D);
    h8 v2 = *(const h8*)(hp + (size_t)i2*D);
    h8 v3 = *(const h8*)(hp + (size_t)i3*D);
    h8 v4 = *(const h8*)(hp + (size_t)i4*D);
    h8 v5 = *(const h8*)(hp + (size_t)i5*D);
    h8 v6 = *(const h8*)(hp + (size_t)i6*D);
    h8 v7 = *(const h8*)(hp + (size_t)i7*D);
    ACC8(v0) ACC8(v1) ACC8(v2) ACC8(v3) ACC8(v4) ACC8(v5) ACC8(v6) ACC8(v7)
  }
  for(; e+4 <= end; e+=4){
    int i0=colidx[e], i1=colidx[e+1], i2=colidx[e+2], i3=colidx[e+3];
    h8 v0 = *(const h8*)(hp + (size_t)i0*D);
    h8 v1 = *(const h8*)(hp + (size_t)i1*D);
    h8 v2 = *(const h8*)(hp + (size_t)i2*D);
    h8 v3 = *(const h8*)(hp + (size_t)i3*D);
    ACC8(v0) ACC8(v1) ACC8(v2) ACC8(v3)
  }
  for(; e < end; e++){
    h8 v = *(const h8*)(hp + (size_t)colidx[e]*D);
    ACC8(v)
  }
#undef ACC8

  float cnt = (end>beg) ? (float)(end-beg) : 1.f;
  h8 vm, vn, vx, vs;
  #pragma unroll
  for(int j = 0; j < 8; j++){
    float a = cs[c+j], b = csh[c+j];
    float mean_r = s[j]/cnt;
    float var_r  = fmaxf(q[j]/cnt - mean_r*mean_r, 0.f);
    float meanp = a*mean_r + b;
    float mnp = (a >= 0.f) ? a*mn[j]+b : a*mx[j]+b;
    float mxp = (a >= 0.f) ? a*mx[j]+b : a*mn[j]+b;
    float sdp = sqrtf(a*a*var_r + EPSV);
    if(end <= beg){ meanp = 0.f; mnp = 0.f; mxp = 0.f; sdp = sqrtf(EPSV); }
    vm[j] = (_Float16)meanp; vn[j] = (_Float16)mnp;
    vx[j] = (_Float16)mxp;   vs[j] = (_Float16)sdp;
  }

  _Float16* dst = aggs + (size_t)(c>>6)*aggN + (size_t)n*256 + (c & 63);
  *(h8*)(dst)       = vm;
  *(h8*)(dst + 64)  = vn;
  *(h8*)(dst + 128) = vx;
  *(h8*)(dst + 192) = vs;
}

// ---------------- fused W pre-pack (all layers/chunks, one kernel) ----------------
// Per chunk slab: Wp[kb=K/32][nt=o/16][lane=64][j=8]; row perm: k<64 -> j0+k ;
// [64,320)->(1+q)d+j0+r ; [320,576)->(5+q)d+j0+r ; [576,832)->(9+q)d+j0+r

struct PackJob { const float* W; _Float16* dst; int d, o, j0, start; };
struct PackArgs { PackJob job[9]; int total; };

__global__ void k_pack_all(PackArgs a){
  int idx = blockIdx.x*256 + threadIdx.x;
  if(idx >= a.total) return;
  int ji = 0;
  while(ji < 8 && idx >= a.job[ji+1].start) ji++;
  PackJob J = a.job[ji];
  int rel = idx - J.start;
  int j    = rel & 7;
  int lane = (rel >> 3) & 63;
  int rem  = rel >> 9;
  int ntiles = J.o >> 4;
  int kb = rem / ntiles;
  int nt = rem - kb*ntiles;
  int k = kb*32 + (lane>>4)*8 + j;
  int n = nt*16 + (lane&15);
  int srcrow;
  if(k < 64)       srcrow = J.j0 + k;
  else if(k < 320){ int t=k-64;  srcrow = (1+(t>>6))*J.d + J.j0 + (t&63); }
  else if(k < 576){ int t=k-320; srcrow = (5+(t>>6))*J.d + J.j0 + (t&63); }
  else            { int t=k-576; srcrow = (9+(t>>6))*J.d + J.j0 + (t&63); }
  J.dst[rel] = (_Float16)J.W[(size_t)srcrow*J.o + n];
}

// ---------------- fused MFMA layer GEMM: 8 waves x 16 rows, LDS-shared B ----------------
// Block = 512 thr = 8 waves x 16 rows = 128 rows, 64 cols. B staged per
// half-chunk (52 KB) and shared by 8 waves. LDS = exactly 53248 B (BN-stat
// reduction arrays ALIAS Bs, which is dead after the K-loop) -> 3 blocks/CU
// -> 24 waves/CU (r17's 53760 B tipped to 2 blocks/CU; that was the regression).
// Epilogue: +bias, ReLU, fp16 store, shuffle-reduced BN stats.

template<int NCH>
__global__ __launch_bounds__(512) void k_mfma_fused(
    const _Float16* __restrict__ actIn,
    const _Float16* __restrict__ aggs,          // [NCH][NN][256], already affine'd
    const float* __restrict__ amp, const float* __restrict__ att,
    const _Float16* __restrict__ cs16, const _Float16* __restrict__ csh16,
    const _Float16* __restrict__ Wp, int o,     // [NCH][832*o]
    const float* __restrict__ bias,
    _Float16* __restrict__ out,                 // [NN][o], relu'd pre-BN
    float* __restrict__ colsum, float* __restrict__ colss)
{
  constexpr int D = NCH * 64;
  __shared__ _Float16 Bs[13*4*64*8];            // 52 KB; red arrays alias it
  int tid  = threadIdx.x;
  int wv   = tid >> 6;       // 0..7
  int lane = tid & 63;
  int mi   = lane & 15;
  int q    = lane >> 4;
  int m0   = blockIdx.y * 128 + wv * 16;
  int c0   = blockIdx.x * 64;
  int ntiles = o >> 4;
  int nt0  = blockIdx.x * 4;

  int mrow = min(m0 + mi, NN-1);
  _Float16 am16 = (_Float16)amp[mrow];
  _Float16 at16 = (_Float16)att[mrow];
  const _Float16* hAb = actIn + (size_t)mrow*D + q*8;
  const _Float16* agb = aggs + (size_t)mrow*256 + q*8;

  f4 acc[4] = {};
  const size_t aggN = (size_t)NN*256;

  #pragma unroll
  for(int c = 0; c < NCH; c++){
    const _Float16* Wpc = Wp + (size_t)c*832*o;

    // ---- A fragments for this chunk (global, issued before staging) ----
    h8 ax[2];
    h8 ag[8];
    #pragma unroll
    for(int kb = 0; kb < 2; kb++){
      h8 sc = *(const h8*)(cs16  + c*64 + kb*32 + q*8);
      h8 sh = *(const h8*)(csh16 + c*64 + kb*32 + q*8);
      h8 a  = *(const h8*)(hAb + c*64 + kb*32);
      ax[kb] = a*sc + sh;
    }
    #pragma unroll
    for(int idx = 0; idx < 8; idx++)
      ag[idx] = *(const h8*)(agb + (size_t)c*aggN + idx*32);

    #pragma unroll
    for(int hf = 0; hf < 2; hf++){
      // ---- stage 52 KB: tiles i = kbL*4+nn for kbL in [0,13) ----
      for(int i = wv; i < 52; i += 8){
        int kb = hf*13 + (i >> 2);
        int nn = i & 3;
        h8 v = *(const h8*)(Wpc + (((size_t)kb*ntiles + nt0 + nn)*64 + lane)*8);
        *(h8*)(&Bs[((size_t)i*64 + lane)*8]) = v;
      }
      __syncthreads();

      // ---- consume: 13 kb x 4 nn MFMAs from LDS ----
      #pragma unroll
      for(int kbL = 0; kbL < 13; kbL++){
        int kb = hf*13 + kbL;
        h8 a;
        if(kb < 2) a = ax[kb];
        else {
          int kb2 = kb - 2, var = kb2 >> 3, idx = kb2 & 7;
          a = (var == 0) ? ag[idx] : (var == 1) ? ag[idx]*am16 : ag[idx]*at16;
        }
        #pragma unroll
        for(int nn = 0; nn < 4; nn++){
          h8 b = *(const h8*)(&Bs[((kbL*4 + nn)*64 + lane)*8]);
          acc[nn] = __builtin_amdgcn_mfma_f32_16x16x32_f16(a, b, acc[nn], 0,0,0);
        }
      }
      __syncthreads();
    }
  }

  // Bs is dead now: reuse its storage for the BN-stat reduction.
  float* redS = (float*)&Bs[0];
  float* redQ = redS + 64;
  if(tid < 64){ redS[tid] = 0.f; redQ[tid] = 0.f; }
  __syncthreads();

  // ---- epilogue: +bias, ReLU, store, stats via q-fold shuffles ----
  #pragma unroll
  for(int nn = 0; nn < 4; nn++){
    int n = c0 + nn*16 + mi;
    float bv = bias[n];
    float ps = 0.f, pq = 0.f;
    #pragma unroll
    for(int r = 0; r < 4; r++){
      int m = m0 + q*4 + r;
      if(m < NN){
        float v = fmaxf(bv + acc[nn][r], 0.f);
        out[(size_t)m*o + n] = (_Float16)v;
        ps += v; pq += v*v;
      }
    }
    ps += __shfl_xor(ps, 16); pq += __shfl_xor(pq, 16);
    ps += __shfl_xor(ps, 32); pq += __shfl_xor(pq, 32);
    if(q == 0){
      atomicAdd(&redS[nn*16 + mi], ps);
      atomicAdd(&redQ[nn*16 + mi], pq);
    }
  }
  __syncthreads();
  if(tid < 64){
    atomicAdd(&colsum[c0 + tid], redS[tid]);
    atomicAdd(&colss[c0 + tid],  redQ[tid]);
  }
}

// ---------------- classifier (applies final BN affine on load) ----------------

__global__ __launch_bounds__(256) void k_cls(const _Float16* __restrict__ h,
    const float* __restrict__ cs, const float* __restrict__ csh,
    const float* __restrict__ Wc, const float* __restrict__ bc,
    float* __restrict__ out){
  __shared__ float w[640];
  __shared__ float bb[16];
  __shared__ float sca[64], shb[64];
  int tid = threadIdx.x;
  for(int i = tid; i < 640; i += 256) w[i] = Wc[i];
  if(tid < 10) bb[tid] = bc[tid];
  if(tid < 64){ sca[tid] = cs[tid]; shb[tid] = csh[tid]; }
  __syncthreads();
  int idx = blockIdx.x*256 + tid;
  int n = idx >> 4;
  int c = idx & 15;
  if(n < NN && c < 10){
    float acc = bb[c];
    const _Float16* hp = h + (size_t)n*64;
    #pragma unroll
    for(int k = 0; k < 64; k++)
      acc += ((float)hp[k]*sca[k] + shb[k]) * w[k*10 + c];
    out[(size_t)n*10 + c] = acc;
  }
}

// ---------------- launch ----------------

extern "C" void kernel_launch(void* const* d_in, const int* in_sizes, int n_in,
                              void* d_out, int out_size, void* d_ws, size_t ws_size,
                              hipStream_t stream){
  const float* x = (const float*)d_in[0];
  const int* edge = (const int*)d_in[1];
  const int* esrc = edge;
  const int* edst = edge + NE;
  const float* W[4]  = {(const float*)d_in[2],  (const float*)d_in[6],
                        (const float*)d_in[10], (const float*)d_in[14]};
  const float* bb[4] = {(const float*)d_in[3],  (const float*)d_in[7],
                        (const float*)d_in[11], (const float*)d_in[15]};
  const float* gm[4] = {(const float*)d_in[4],  (const float*)d_in[8],
                        (const float*)d_in[12], (const float*)d_in[16]};
  const float* bt[4] = {(const float*)d_in[5],  (const float*)d_in[9],
                        (const float*)d_in[13], (const float*)d_in[17]};
  const float* Wc = (const float*)d_in[18];
  const float* bc = (const float*)d_in[19];
  (void)in_sizes; (void)n_in; (void)out_size; (void)ws_size;

  // workspace carve (~158 MB; proven-safe envelope)
  char* p = (char*)d_ws;
  auto alloc = [&](size_t bytes)->char*{
    char* r = p; p += (bytes + 255) & ~(size_t)255; return r;
  };
  _Float16* act0 = (_Float16*)alloc((size_t)NN*256*2);   // 25.6 MB
  _Float16* act1 = (_Float16*)alloc((size_t)NN*256*2);   // 25.6 MB
  _Float16* aggs = (_Float16*)alloc((size_t)4*NN*256*2); // 102.4 MB: [chunk][N][256]
  int*   deg    = (int*)  alloc((size_t)NN*4);
  float* logdeg = (float*)alloc((size_t)NN*4);
  float* amp    = (float*)alloc((size_t)NN*4);
  float* att    = (float*)alloc((size_t)NN*4);
  int*   rowptr = (int*)  alloc((size_t)(NN+1)*4);
  int*   cursor = (int*)  alloc((size_t)NN*4);
  int*   colidx = (int*)  alloc((size_t)NE*4);
  int*   bsum   = (int*)  alloc((size_t)(NB+1)*4);
  float* colsumL= (float*)alloc(4*256*4);   // per-layer BN partials
  float* colssL = (float*)alloc(4*256*4);
  float* dsum   = (float*)alloc(256);
  // BN coefficient double-buffers (fp32 + fp16)
  float*    csA  = (float*)   alloc(256*4);
  float*    cshA = (float*)   alloc(256*4);
  float*    csB  = (float*)   alloc(256*4);
  float*    cshB = (float*)   alloc(256*4);
  _Float16* cs16A  = (_Float16*)alloc(256*2);
  _Float16* csh16A = (_Float16*)alloc(256*2);
  _Float16* cs16B  = (_Float16*)alloc(256*2);
  _Float16* csh16B = (_Float16*)alloc(256*2);

  const int din[4]  = {64, 128, 256, 128};
  const int dto[4]  = {128, 256, 128, 64};
  const size_t aggN = (size_t)NN*256;      // halves per chunk slab
  _Float16* WpL[4];
  PackArgs pa; int pj = 0, poff = 0;
  for(int l = 0; l < 4; l++){
    int nch = din[l]/64;
    WpL[l] = (_Float16*)alloc((size_t)nch*832*dto[l]*2);
    for(int c = 0; c < nch; c++){
      pa.job[pj] = { W[l], WpL[l] + (size_t)c*832*dto[l], din[l], dto[l], c*64, poff };
      poff += 832*dto[l]; pj++;
    }
  }
  pa.total = poff;

  hipMemsetAsync(deg, 0, (size_t)NN*4, stream);
  hipMemsetAsync(dsum, 0, 4, stream);
  hipMemsetAsync(colsumL, 0, 4*256*4, stream);
  hipMemsetAsync(colssL,  0, 4*256*4, stream);

  k_pack_all<<<(pa.total+255)/256, 256, 0, stream>>>(pa);
  k_deg     <<<(NE+255)/256, 256, 0, stream>>>(edst, deg);
  k_logdeg  <<<(NN+255)/256, 256, 0, stream>>>(deg, logdeg, dsum);
  k_scalers <<<(NN+255)/256, 256, 0, stream>>>(logdeg, dsum, amp, att);
  k_scan1   <<<NB, 1024, 0, stream>>>(deg, rowptr, bsum);
  k_scan2   <<<1, 64, 0, stream>>>(bsum);
  k_scan3   <<<(NN+256)/256, 256, 0, stream>>>(rowptr, cursor, bsum);
  k_fill    <<<(NE+255)/256, 256, 0, stream>>>(esrc, edst, cursor, colidx);
  k_cvtx    <<<(NN*64+255)/256, 256, 0, stream>>>(x, act0);
  k_coef_id <<<1, 256, 0, stream>>>(csA, cshA, cs16A, csh16A);

  _Float16* actIn = act0;  _Float16* actOut = act1;
  float *csI = csA, *cshI = cshA, *csO = csB, *cshO = cshB;
  _Float16 *cs16I = cs16A, *csh16I = csh16A, *cs16O = cs16B, *csh16O = csh16B;

  for(int l = 0; l < 4; l++){
    int d = din[l], o = dto[l];
    int npb = (64 / (d >> 3)) * 4;          // nodes per block in k_agg8
    int nagg = (NN + npb - 1) / npb;
    dim3 g(o/64, (NN+127)/128);
    float* csum = colsumL + l*256;
    float* csq  = colssL + l*256;
    switch(d){
      case 64:
        k_agg8<64><<<nagg, 256, 0, stream>>>(actIn, rowptr, colidx, csI, cshI, aggs, aggN);
        k_mfma_fused<1><<<g, 512, 0, stream>>>(actIn, aggs, amp, att, cs16I, csh16I,
                                               WpL[l], o, bb[l], actOut, csum, csq);
        break;
      case 128:
        k_agg8<128><<<nagg, 256, 0, stream>>>(actIn, rowptr, colidx, csI, cshI, aggs, aggN);
        k_mfma_fused<2><<<g, 512, 0, stream>>>(actIn, aggs, amp, att, cs16I, csh16I,
                                               WpL[l], o, bb[l], actOut, csum, csq);
        break;
      default:
        k_agg8<256><<<nagg, 256, 0, stream>>>(actIn, rowptr, colidx, csI, cshI, aggs, aggN);
        k_mfma_fused<4><<<g, 512, 0, stream>>>(actIn, aggs, amp, att, cs16I, csh16I,
                                               WpL[l], o, bb[l], actOut, csum, csq);
        break;
    }
    k_bn_coef<<<1, 256, 0, stream>>>(csum, csq, gm[l], bt[l], o,
                                     csO, cshO, cs16O, csh16O);
    // swap activation and coefficient buffers
    _Float16* ta = actIn; actIn = actOut; actOut = ta;
    float* tf;
    tf = csI;  csI = csO;  csO = tf;
    tf = cshI; cshI = cshO; cshO = tf;
    _Float16* th;
    th = cs16I;  cs16I = cs16O;  cs16O = th;
    th = csh16I; csh16I = csh16O; csh16O = th;
  }
  k_cls<<<(NN*16+255)/256, 256, 0, stream>>>(actIn, csI, cshI, Wc, bc, (float*)d_out);
}

// Round 19
// 697.963 us; speedup vs baseline: 1.0625x; 1.0625x over previous
//
#include <hip/hip_runtime.h>
#include <hip/hip_bf16.h>

#define NN 50000
#define NE 800000
#define EPSV 1e-5f
#define NB 49   // scan blocks: ceil(NN/1024)

typedef _Float16 h8 __attribute__((ext_vector_type(8)));
typedef float    f4 __attribute__((ext_vector_type(4)));

// ---------------- graph preprocessing ----------------

__global__ void k_deg(const int* __restrict__ dst, int* __restrict__ deg){
  int e = blockIdx.x*blockDim.x + threadIdx.x;
  if(e < NE) atomicAdd(&deg[dst[e]], 1);
}

__global__ void k_logdeg(const int* __restrict__ deg, float* __restrict__ logdeg,
                         float* __restrict__ dsum){
  int i = blockIdx.x*blockDim.x + threadIdx.x;
  float v = 0.f;
  if(i < NN){ v = log1pf((float)deg[i]); logdeg[i] = v; }
  __shared__ float sh[256];
  sh[threadIdx.x] = v; __syncthreads();
  for(int off=128; off>0; off>>=1){
    if(threadIdx.x < off) sh[threadIdx.x] += sh[threadIdx.x+off];
    __syncthreads();
  }
  if(threadIdx.x == 0) atomicAdd(dsum, sh[0]);
}

__global__ void k_scalers(const float* __restrict__ logdeg, const float* __restrict__ dsum,
                          float* __restrict__ amp, float* __restrict__ att){
  int i = blockIdx.x*blockDim.x + threadIdx.x;
  if(i >= NN) return;
  float delta = dsum[0] / (float)NN;
  float ld = logdeg[i];
  amp[i] = ld / delta;
  att[i] = (ld > 0.f) ? (delta / fmaxf(ld, 1e-6f)) : 1.f;
}

// 3-phase parallel exclusive scan of deg -> rowptr (+cursor copy)
__global__ void k_scan1(const int* __restrict__ deg, int* __restrict__ rowptr,
                        int* __restrict__ bsum){
  __shared__ int buf[1024];
  int tid = threadIdx.x;
  int i = blockIdx.x*1024 + tid;
  int v = (i < NN) ? deg[i] : 0;
  buf[tid] = v; __syncthreads();
  for(int off=1; off<1024; off<<=1){
    int t = (tid >= off) ? buf[tid-off] : 0;
    __syncthreads();
    buf[tid] += t;
    __syncthreads();
  }
  if(i < NN) rowptr[i] = buf[tid] - v;
  if(tid == 1023) bsum[blockIdx.x] = buf[1023];
}

__global__ void k_scan2(int* __restrict__ bsum){
  if(threadIdx.x == 0){
    int s = 0;
    for(int b = 0; b < NB; b++){ int t = bsum[b]; bsum[b] = s; s += t; }
    bsum[NB] = s;
  }
}

__global__ void k_scan3(int* __restrict__ rowptr, int* __restrict__ cursor,
                        const int* __restrict__ bsum){
  int i = blockIdx.x*256 + threadIdx.x;
  if(i < NN){
    int v = rowptr[i] + bsum[i >> 10];
    rowptr[i] = v; cursor[i] = v;
  }
  if(i == NN) rowptr[NN] = bsum[NB];
}

__global__ void k_fill(const int* __restrict__ src, const int* __restrict__ dst,
                       int* __restrict__ cursor, int* __restrict__ colidx){
  int e = blockIdx.x*blockDim.x + threadIdx.x;
  if(e < NE){
    int pos = atomicAdd(&cursor[dst[e]], 1);
    colidx[pos] = src[e];
  }
}

__global__ void k_cvtx(const float* __restrict__ x, _Float16* __restrict__ act){
  int i = blockIdx.x*256 + threadIdx.x;
  if(i < NN*64) act[i] = (_Float16)x[i];
}

// identity BN coefficients for layer 1
__global__ void k_coef_id(float* __restrict__ cs, float* __restrict__ csh,
                          _Float16* __restrict__ cs16, _Float16* __restrict__ csh16){
  int c = threadIdx.x;
  cs[c] = 1.f; csh[c] = 0.f;
  cs16[c] = (_Float16)1.f; csh16[c] = (_Float16)0.f;
}

// BN coefficients from stats: v' = a*v + b with a=inv*gamma, b=beta-mean*a
__global__ void k_bn_coef(const float* __restrict__ colsum, const float* __restrict__ colss,
                          const float* __restrict__ gamma, const float* __restrict__ beta,
                          int dout, float* __restrict__ cs, float* __restrict__ csh,
                          _Float16* __restrict__ cs16, _Float16* __restrict__ csh16){
  int c = threadIdx.x;
  if(c >= dout) return;
  float mean = colsum[c] / (float)NN;
  float var  = colss[c] / (float)NN - mean*mean;
  float inv  = rsqrtf(fmaxf(var, 0.f) + EPSV);
  float a = inv * gamma[c];
  float b = beta[c] - mean * a;
  cs[c] = a; csh[c] = b;
  cs16[c] = (_Float16)a; csh16[c] = (_Float16)b;
}

// ---------------- aggregation (templated on D): 8 cols/lane, 16 B loads ----------------
// Reads RAW act; applies per-column affine (a,b) in the epilogue:
// mean'=a*mean+b ; min/max swap on a<0 ; std'=sqrt(a^2*var+eps).
// aggs[chunk][n*256 + {0,64,128,192} + cl] = mean|min|max|std

template<int D>
__global__ __launch_bounds__(256) void k_agg8(
    const _Float16* __restrict__ act,
    const int* __restrict__ rowptr, const int* __restrict__ colidx,
    const float* __restrict__ cs, const float* __restrict__ csh,
    _Float16* __restrict__ aggs, size_t aggN)
{
  constexpr int LPN = D >> 3;       // lanes per node: 8/16/32
  constexpr int NPW = 64 / LPN;     // nodes per wave: 8/4/2
  int wv = threadIdx.x >> 6, lane = threadIdx.x & 63;
  int n = blockIdx.x*(NPW*4) + wv*NPW + (lane / LPN);
  int c = (lane % LPN) * 8;         // 8 adjacent feature cols
  if(n >= NN) return;
  int beg = rowptr[n], end = rowptr[n+1];
  const _Float16* hp = act + c;

  float s[8], q[8], mn[8], mx[8];
  #pragma unroll
  for(int j = 0; j < 8; j++){ s[j]=0.f; q[j]=0.f; mn[j]=INFINITY; mx[j]=-INFINITY; }

#define ACC8(v) { _Pragma("unroll") for(int j=0;j<8;j++){ float a=(float)(v)[j]; \
    s[j]+=a; q[j]+=a*a; mn[j]=fminf(mn[j],a); mx[j]=fmaxf(mx[j],a); } }

  int e = beg;
  for(; e+8 <= end; e+=8){
    int i0=colidx[e],   i1=colidx[e+1], i2=colidx[e+2], i3=colidx[e+3];
    int i4=colidx[e+4], i5=colidx[e+5], i6=colidx[e+6], i7=colidx[e+7];
    h8 v0 = *(const h8*)(hp + (size_t)i0*D);
    h8 v1 = *(const h8*)(hp + (size_t)i1*D);
    h8 v2 = *(const h8*)(hp + (size_t)i2*D);
    h8 v3 = *(const h8*)(hp + (size_t)i3*D);
    h8 v4 = *(const h8*)(hp + (size_t)i4*D);
    h8 v5 = *(const h8*)(hp + (size_t)i5*D);
    h8 v6 = *(const h8*)(hp + (size_t)i6*D);
    h8 v7 = *(const h8*)(hp + (size_t)i7*D);
    ACC8(v0) ACC8(v1) ACC8(v2) ACC8(v3) ACC8(v4) ACC8(v5) ACC8(v6) ACC8(v7)
  }
  for(; e+4 <= end; e+=4){
    int i0=colidx[e], i1=colidx[e+1], i2=colidx[e+2], i3=colidx[e+3];
    h8 v0 = *(const h8*)(hp + (size_t)i0*D);
    h8 v1 = *(const h8*)(hp + (size_t)i1*D);
    h8 v2 = *(const h8*)(hp + (size_t)i2*D);
    h8 v3 = *(const h8*)(hp + (size_t)i3*D);
    ACC8(v0) ACC8(v1) ACC8(v2) ACC8(v3)
  }
  for(; e < end; e++){
    h8 v = *(const h8*)(hp + (size_t)colidx[e]*D);
    ACC8(v)
  }
#undef ACC8

  float cnt = (end>beg) ? (float)(end-beg) : 1.f;
  h8 vm, vn, vx, vs;
  #pragma unroll
  for(int j = 0; j < 8; j++){
    float a = cs[c+j], b = csh[c+j];
    float mean_r = s[j]/cnt;
    float var_r  = fmaxf(q[j]/cnt - mean_r*mean_r, 0.f);
    float meanp = a*mean_r + b;
    float mnp = (a >= 0.f) ? a*mn[j]+b : a*mx[j]+b;
    float mxp = (a >= 0.f) ? a*mx[j]+b : a*mn[j]+b;
    float sdp = sqrtf(a*a*var_r + EPSV);
    if(end <= beg){ meanp = 0.f; mnp = 0.f; mxp = 0.f; sdp = sqrtf(EPSV); }
    vm[j] = (_Float16)meanp; vn[j] = (_Float16)mnp;
    vx[j] = (_Float16)mxp;   vs[j] = (_Float16)sdp;
  }

  _Float16* dst = aggs + (size_t)(c>>6)*aggN + (size_t)n*256 + (c & 63);
  *(h8*)(dst)       = vm;
  *(h8*)(dst + 64)  = vn;
  *(h8*)(dst + 128) = vx;
  *(h8*)(dst + 192) = vs;
}

// ---------------- fused W pre-pack (all layers/chunks, one kernel) ----------------
// Per chunk slab: Wp[kb=K/32][nt=o/16][lane=64][j=8]; row perm: k<64 -> j0+k ;
// [64,320)->(1+q)d+j0+r ; [320,576)->(5+q)d+j0+r ; [576,832)->(9+q)d+j0+r

struct PackJob { const float* W; _Float16* dst; int d, o, j0, start; };
struct PackArgs { PackJob job[9]; int total; };

__global__ void k_pack_all(PackArgs a){
  int idx = blockIdx.x*256 + threadIdx.x;
  if(idx >= a.total) return;
  int ji = 0;
  while(ji < 8 && idx >= a.job[ji+1].start) ji++;
  PackJob J = a.job[ji];
  int rel = idx - J.start;
  int j    = rel & 7;
  int lane = (rel >> 3) & 63;
  int rem  = rel >> 9;
  int ntiles = J.o >> 4;
  int kb = rem / ntiles;
  int nt = rem - kb*ntiles;
  int k = kb*32 + (lane>>4)*8 + j;
  int n = nt*16 + (lane&15);
  int srcrow;
  if(k < 64)       srcrow = J.j0 + k;
  else if(k < 320){ int t=k-64;  srcrow = (1+(t>>6))*J.d + J.j0 + (t&63); }
  else if(k < 576){ int t=k-320; srcrow = (5+(t>>6))*J.d + J.j0 + (t&63); }
  else            { int t=k-576; srcrow = (9+(t>>6))*J.d + J.j0 + (t&63); }
  J.dst[rel] = (_Float16)J.W[(size_t)srcrow*J.o + n];
}

// ---------------- fused MFMA layer GEMM (templated NCH; r16 = measured best) ----------------
// r9 geometry: 4 waves x 32 rows = 128 rows, 64 cols. x-phase A-frags get
// BN affine; epilogue: +bias, ReLU, fp16 store, shuffle-reduced BN stats.
// NOTE: 9 structural variants (B via LDS / register prefetch / tile reshapes)
// all landed at 103-150 us for the big layer; this configuration is the
// measured optimum of the family. See session journal r9-r18.

template<int NCH>
__global__ __launch_bounds__(256) void k_mfma_fused(
    const _Float16* __restrict__ actIn,
    const _Float16* __restrict__ aggs,          // [NCH][NN][256], already affine'd
    const float* __restrict__ amp, const float* __restrict__ att,
    const _Float16* __restrict__ cs16, const _Float16* __restrict__ csh16,
    const _Float16* __restrict__ Wp, int o,     // [NCH][832*o]
    const float* __restrict__ bias,
    _Float16* __restrict__ out,                 // [NN][o], relu'd pre-BN
    float* __restrict__ colsum, float* __restrict__ colss)
{
  constexpr int D = NCH * 64;
  __shared__ float redS[64], redQ[64];
  int tid  = threadIdx.x;
  int wv   = tid >> 6;
  int lane = tid & 63;
  int mi   = lane & 15;
  int q    = lane >> 4;
  int m0   = blockIdx.y * 128 + wv * 32;
  int c0   = blockIdx.x * 64;
  int ntiles = o >> 4;
  int nt0  = blockIdx.x * 4;

  if(tid < 64){ redS[tid] = 0.f; redQ[tid] = 0.f; }

  int mrow[2];
  mrow[0] = min(m0 + mi,      NN-1);
  mrow[1] = min(m0 + 16 + mi, NN-1);
  _Float16 am16[2] = { (_Float16)amp[mrow[0]], (_Float16)amp[mrow[1]] };
  _Float16 at16[2] = { (_Float16)att[mrow[0]], (_Float16)att[mrow[1]] };
  const _Float16* hAb[2];
  const _Float16* agb[2];
  hAb[0] = actIn + (size_t)mrow[0]*D + q*8;
  hAb[1] = actIn + (size_t)mrow[1]*D + q*8;
  agb[0] = aggs + (size_t)mrow[0]*256 + q*8;
  agb[1] = aggs + (size_t)mrow[1]*256 + q*8;

  f4 acc[2][4] = {};
  const size_t aggN = (size_t)NN*256;

  #pragma unroll
  for(int c = 0; c < NCH; c++){
    const _Float16* Wpc = Wp + (size_t)c*832*o;
    auto bfrag = [&](int kb, int nn) -> h8 {
      return *(const h8*)(Wpc + (((size_t)kb*ntiles + nt0 + nn)*64 + lane)*8);
    };

    // ---- A fragments (prefetch): x-phase with BN affine, aggs raw ----
    h8 ax[2][2];
    h8 ag[8][2];
    #pragma unroll
    for(int kb = 0; kb < 2; kb++){
      h8 sc = *(const h8*)(cs16  + c*64 + kb*32 + q*8);
      h8 sh = *(const h8*)(csh16 + c*64 + kb*32 + q*8);
      #pragma unroll
      for(int t = 0; t < 2; t++){
        h8 a = *(const h8*)(hAb[t] + c*64 + kb*32);
        ax[kb][t] = a*sc + sh;
      }
    }
    #pragma unroll
    for(int idx = 0; idx < 8; idx++)
      #pragma unroll
      for(int t = 0; t < 2; t++)
        ag[idx][t] = *(const h8*)(agb[t] + (size_t)c*aggN + idx*32);

    // ---- phase X: kb = 0,1 ----
    #pragma unroll
    for(int kb = 0; kb < 2; kb++)
      #pragma unroll
      for(int t = 0; t < 2; t++)
        #pragma unroll
        for(int nn = 0; nn < 4; nn++)
          acc[t][nn] = __builtin_amdgcn_mfma_f32_16x16x32_f16(ax[kb][t], bfrag(kb,nn), acc[t][nn], 0,0,0);

    // ---- aggs phases: plain / amp-scaled / att-scaled ----
    #pragma unroll
    for(int idx = 0; idx < 8; idx++){
      #pragma unroll
      for(int t = 0; t < 2; t++){
        h8 apl = ag[idx][t];
        h8 aam = apl * am16[t];
        h8 aat = apl * at16[t];
        #pragma unroll
        for(int nn = 0; nn < 4; nn++){
          acc[t][nn] = __builtin_amdgcn_mfma_f32_16x16x32_f16(apl, bfrag(2+idx,  nn), acc[t][nn], 0,0,0);
          acc[t][nn] = __builtin_amdgcn_mfma_f32_16x16x32_f16(aam, bfrag(10+idx, nn), acc[t][nn], 0,0,0);
          acc[t][nn] = __builtin_amdgcn_mfma_f32_16x16x32_f16(aat, bfrag(18+idx, nn), acc[t][nn], 0,0,0);
        }
      }
    }
  }

  __syncthreads();   // redS/redQ zero-init visible

  // ---- epilogue: +bias, ReLU, store, stats via q-fold shuffles ----
  #pragma unroll
  for(int nn = 0; nn < 4; nn++){
    int n = c0 + nn*16 + mi;
    float bv = bias[n];
    float ps = 0.f, pq = 0.f;
    #pragma unroll
    for(int t = 0; t < 2; t++){
      #pragma unroll
      for(int r = 0; r < 4; r++){
        int m = m0 + t*16 + q*4 + r;
        if(m < NN){
          float v = fmaxf(bv + acc[t][nn][r], 0.f);
          out[(size_t)m*o + n] = (_Float16)v;
          ps += v; pq += v*v;
        }
      }
    }
    ps += __shfl_xor(ps, 16); pq += __shfl_xor(pq, 16);
    ps += __shfl_xor(ps, 32); pq += __shfl_xor(pq, 32);
    if(q == 0){
      atomicAdd(&redS[nn*16 + mi], ps);
      atomicAdd(&redQ[nn*16 + mi], pq);
    }
  }
  __syncthreads();
  if(tid < 64){
    atomicAdd(&colsum[c0 + tid], redS[tid]);
    atomicAdd(&colss[c0 + tid],  redQ[tid]);
  }
}

// ---------------- classifier (applies final BN affine on load) ----------------

__global__ __launch_bounds__(256) void k_cls(const _Float16* __restrict__ h,
    const float* __restrict__ cs, const float* __restrict__ csh,
    const float* __restrict__ Wc, const float* __restrict__ bc,
    float* __restrict__ out){
  __shared__ float w[640];
  __shared__ float bb[16];
  __shared__ float sca[64], shb[64];
  int tid = threadIdx.x;
  for(int i = tid; i < 640; i += 256) w[i] = Wc[i];
  if(tid < 10) bb[tid] = bc[tid];
  if(tid < 64){ sca[tid] = cs[tid]; shb[tid] = csh[tid]; }
  __syncthreads();
  int idx = blockIdx.x*256 + tid;
  int n = idx >> 4;
  int c = idx & 15;
  if(n < NN && c < 10){
    float acc = bb[c];
    const _Float16* hp = h + (size_t)n*64;
    #pragma unroll
    for(int k = 0; k < 64; k++)
      acc += ((float)hp[k]*sca[k] + shb[k]) * w[k*10 + c];
    out[(size_t)n*10 + c] = acc;
  }
}

// ---------------- launch ----------------

extern "C" void kernel_launch(void* const* d_in, const int* in_sizes, int n_in,
                              void* d_out, int out_size, void* d_ws, size_t ws_size,
                              hipStream_t stream){
  const float* x = (const float*)d_in[0];
  const int* edge = (const int*)d_in[1];
  const int* esrc = edge;
  const int* edst = edge + NE;
  const float* W[4]  = {(const float*)d_in[2],  (const float*)d_in[6],
                        (const float*)d_in[10], (const float*)d_in[14]};
  const float* bb[4] = {(const float*)d_in[3],  (const float*)d_in[7],
                        (const float*)d_in[11], (const float*)d_in[15]};
  const float* gm[4] = {(const float*)d_in[4],  (const float*)d_in[8],
                        (const float*)d_in[12], (const float*)d_in[16]};
  const float* bt[4] = {(const float*)d_in[5],  (const float*)d_in[9],
                        (const float*)d_in[13], (const float*)d_in[17]};
  const float* Wc = (const float*)d_in[18];
  const float* bc = (const float*)d_in[19];
  (void)in_sizes; (void)n_in; (void)out_size; (void)ws_size;

  // workspace carve (~158 MB; proven-safe envelope)
  char* p = (char*)d_ws;
  auto alloc = [&](size_t bytes)->char*{
    char* r = p; p += (bytes + 255) & ~(size_t)255; return r;
  };
  _Float16* act0 = (_Float16*)alloc((size_t)NN*256*2);   // 25.6 MB
  _Float16* act1 = (_Float16*)alloc((size_t)NN*256*2);   // 25.6 MB
  _Float16* aggs = (_Float16*)alloc((size_t)4*NN*256*2); // 102.4 MB: [chunk][N][256]
  int*   deg    = (int*)  alloc((size_t)NN*4);
  float* logdeg = (float*)alloc((size_t)NN*4);
  float* amp    = (float*)alloc((size_t)NN*4);
  float* att    = (float*)alloc((size_t)NN*4);
  int*   rowptr = (int*)  alloc((size_t)(NN+1)*4);
  int*   cursor = (int*)  alloc((size_t)NN*4);
  int*   colidx = (int*)  alloc((size_t)NE*4);
  int*   bsum   = (int*)  alloc((size_t)(NB+1)*4);
  float* colsumL= (float*)alloc(4*256*4);   // per-layer BN partials
  float* colssL = (float*)alloc(4*256*4);
  float* dsum   = (float*)alloc(256);
  // BN coefficient double-buffers (fp32 + fp16)
  float*    csA  = (float*)   alloc(256*4);
  float*    cshA = (float*)   alloc(256*4);
  float*    csB  = (float*)   alloc(256*4);
  float*    cshB = (float*)   alloc(256*4);
  _Float16* cs16A  = (_Float16*)alloc(256*2);
  _Float16* csh16A = (_Float16*)alloc(256*2);
  _Float16* cs16B  = (_Float16*)alloc(256*2);
  _Float16* csh16B = (_Float16*)alloc(256*2);

  const int din[4]  = {64, 128, 256, 128};
  const int dto[4]  = {128, 256, 128, 64};
  const size_t aggN = (size_t)NN*256;      // halves per chunk slab
  _Float16* WpL[4];
  PackArgs pa; int pj = 0, poff = 0;
  for(int l = 0; l < 4; l++){
    int nch = din[l]/64;
    WpL[l] = (_Float16*)alloc((size_t)nch*832*dto[l]*2);
    for(int c = 0; c < nch; c++){
      pa.job[pj] = { W[l], WpL[l] + (size_t)c*832*dto[l], din[l], dto[l], c*64, poff };
      poff += 832*dto[l]; pj++;
    }
  }
  pa.total = poff;

  hipMemsetAsync(deg, 0, (size_t)NN*4, stream);
  hipMemsetAsync(dsum, 0, 4, stream);
  hipMemsetAsync(colsumL, 0, 4*256*4, stream);
  hipMemsetAsync(colssL,  0, 4*256*4, stream);

  k_pack_all<<<(pa.total+255)/256, 256, 0, stream>>>(pa);
  k_deg     <<<(NE+255)/256, 256, 0, stream>>>(edst, deg);
  k_logdeg  <<<(NN+255)/256, 256, 0, stream>>>(deg, logdeg, dsum);
  k_scalers <<<(NN+255)/256, 256, 0, stream>>>(logdeg, dsum, amp, att);
  k_scan1   <<<NB, 1024, 0, stream>>>(deg, rowptr, bsum);
  k_scan2   <<<1, 64, 0, stream>>>(bsum);
  k_scan3   <<<(NN+256)/256, 256, 0, stream>>>(rowptr, cursor, bsum);
  k_fill    <<<(NE+255)/256, 256, 0, stream>>>(esrc, edst, cursor, colidx);
  k_cvtx    <<<(NN*64+255)/256, 256, 0, stream>>>(x, act0);
  k_coef_id <<<1, 256, 0, stream>>>(csA, cshA, cs16A, csh16A);

  _Float16* actIn = act0;  _Float16* actOut = act1;
  float *csI = csA, *cshI = cshA, *csO = csB, *cshO = cshB;
  _Float16 *cs16I = cs16A, *csh16I = csh16A, *cs16O = cs16B, *csh16O = csh16B;

  for(int l = 0; l < 4; l++){
    int d = din[l], o = dto[l];
    int npb = (64 / (d >> 3)) * 4;          // nodes per block in k_agg8
    int nagg = (NN + npb - 1) / npb;
    dim3 g(o/64, (NN+127)/128);
    float* csum = colsumL + l*256;
    float* csq  = colssL + l*256;
    switch(d){
      case 64:
        k_agg8<64><<<nagg, 256, 0, stream>>>(actIn, rowptr, colidx, csI, cshI, aggs, aggN);
        k_mfma_fused<1><<<g, 256, 0, stream>>>(actIn, aggs, amp, att, cs16I, csh16I,
                                               WpL[l], o, bb[l], actOut, csum, csq);
        break;
      case 128:
        k_agg8<128><<<nagg, 256, 0, stream>>>(actIn, rowptr, colidx, csI, cshI, aggs, aggN);
        k_mfma_fused<2><<<g, 256, 0, stream>>>(actIn, aggs, amp, att, cs16I, csh16I,
                                               WpL[l], o, bb[l], actOut, csum, csq);
        break;
      default:
        k_agg8<256><<<nagg, 256, 0, stream>>>(actIn, rowptr, colidx, csI, cshI, aggs, aggN);
        k_mfma_fused<4><<<g, 256, 0, stream>>>(actIn, aggs, amp, att, cs16I, csh16I,
                                               WpL[l], o, bb[l], actOut, csum, csq);
        break;
    }
    k_bn_coef<<<1, 256, 0, stream>>>(csum, csq, gm[l], bt[l], o,
                                     csO, cshO, cs16O, csh16O);
    // swap activation and coefficient buffers
    _Float16* ta = actIn; actIn = actOut; actOut = ta;
    float* tf;
    tf = csI;  csI = csO;  csO = tf;
    tf = cshI; cshI = cshO; cshO = tf;
    _Float16* th;
    th = cs16I;  cs16I = cs16O;  cs16O = th;
    th = csh16I; csh16I = csh16O; csh16O = th;
  }
  k_cls<<<(NN*16+255)/256, 256, 0, stream>>>(actIn, csI, cshI, Wc, bc, (float*)d_out);
}